// Round 15
// baseline (77.590 us; speedup 1.0000x reference)
//
#include <hip/hip_runtime.h>
#include <hip/hip_bf16.h>
#include <cstdint>
#include <cmath>

typedef unsigned long long u64;

// ---------------------------------------------------------------------------
// SparseLinear: out[b, dst[e]] += values[e] * x[b, src[e]]; out += bias
// Round 15: scatter occupancy 1 -> 2 blocks/CU (SC_EDGES 4096->2048 + u16
// binbase => ~30KB LDS <= 32KB); detect/cursor-zero fused into prep (one
// fewer launch). R14 analysis: scatter streamed 32MB at only ~1.2TB/s with
// 53.5KB LDS capping it at 16 waves/CU.
// Journal: 51.2M ds_add_f32 atomics had a ~283us floor (R9 ablation) ->
// counting-sort + register accumulation was the 10x lever. nt-stores on
// scattered 8B records caused 5.4x HBM write amplification (R11->R12).
// Packed edge record: [63:32]=val bits, [31:6]=src, [4:0]=dst&31.
// ---------------------------------------------------------------------------

#define RB        32          // rows per bucket
#define RB_SHIFT  5
#define SREC_MAX  2048        // max records per bucket stageable in LDS (reduce)

// K1: transpose x (32, N) -> xt (N, 32) in bf16 (LDS 32x33 tile), fused with
// int64-detect (block 0) and cursor zeroing (distributed across blocks).
__global__ void SL_prep_kernel(const float* __restrict__ x, __hip_bfloat16* __restrict__ xt,
                               int N, const uint32_t* __restrict__ raw,
                               int* __restrict__ flag, int* __restrict__ cursor, int NB) {
    __shared__ float tile[32][33];
    int tx = threadIdx.x, ty = threadIdx.y;
    int tl = ty * 32 + tx;                       // linear 0..1023
    int gid = blockIdx.x * 1024 + tl;
    if (gid < NB) cursor[gid] = 0;
    if (blockIdx.x == 0 && tl == 0) {
        int is64 = 1;
        for (int i = 1; i < 64; i += 2) {
            if (raw[i] != 0u) { is64 = 0; break; }
        }
        *flag = is64;
    }
    int n0 = blockIdx.x * 32;
    int n = n0 + tx;
    if (n < N) tile[tx][ty] = x[(size_t)ty * N + n];
    __syncthreads();
    int n2 = n0 + ty;
    if (n2 < N) xt[(size_t)n2 * 32 + tx] = __float2bfloat16(tile[ty][tx]);
}

// K2: bucket scatter with in-block counting sort (wave-shfl scan, 2 barriers).
// 1024 threads x 2 edges = 2048 edges/block; ~30KB LDS -> 2 blocks/CU.
#define SC_BLOCK 1024
#define SC_EPT   2
#define SC_EDGES (SC_BLOCK * SC_EPT)   // 2048
#define SC_WAVES (SC_BLOCK / 64)       // 16
__global__ __launch_bounds__(SC_BLOCK)
void SL_bucket_scatter_kernel(const int* __restrict__ raw, const int* __restrict__ flag,
                              const float* __restrict__ vals, u64* __restrict__ packed,
                              int* __restrict__ cursor, long long E, int NB, int CAP) {
    extern __shared__ char lds_raw[];
    u64* srec = (u64*)lds_raw;                               // SC_EDGES u64 (16KB)
    int* hist = (int*)(srec + SC_EDGES);                     // NB ints; gbase after ph2
    int* wsum = hist + NB;                                   // 16 ints
    unsigned short* binbase = (unsigned short*)(wsum + 16);  // NB u16 (ranks < 2048)
    unsigned short* bkts    = binbase + NB;                  // SC_EDGES u16

    const int tid  = threadIdx.x;
    const int lane = tid & 63;
    const int wid  = tid >> 6;
    for (int i = tid; i < NB; i += SC_BLOCK) hist[i] = 0;
    __syncthreads();

    const int is64 = *flag;
    const long long base_e = (long long)blockIdx.x * SC_EDGES;
    const long long* raw64 = (const long long*)raw;

    // Phase 1 — rank + cache src/val in registers.
    int   rp[SC_EPT];
    int   sv[SC_EPT];
    float vv[SC_EPT];
#pragma unroll
    for (int j = 0; j < SC_EPT; ++j) {
        long long e = base_e + tid + (long long)j * SC_BLOCK;
        int v = -1;
        if (e < E) {
            int d = is64 ? (int)raw64[E + e] : raw[E + e];
            sv[j] = is64 ? (int)raw64[e] : raw[e];
            vv[j] = vals[e];
            int bkt = d >> RB_SHIFT;
            int rank = atomicAdd(&hist[bkt], 1);
            v = (bkt << 19) | ((d & (RB - 1)) << 14) | rank;
        } else { sv[j] = 0; vv[j] = 0.0f; }
        rp[j] = v;
    }
    __syncthreads();

    // Phase 2 — wave-shfl scan (block-exclusive binbase) + global reservation.
    const int C = (NB + SC_BLOCK - 1) / SC_BLOCK;    // bins per thread (<=2)
    int lo = tid * C, hi = lo + C;
    if (lo > NB) lo = NB;
    if (hi > NB) hi = NB;
    int sown = 0;
    for (int i = lo; i < hi; ++i) sown += hist[i];
    int s = sown;
#pragma unroll
    for (int o = 1; o < 64; o <<= 1) {        // wave inclusive scan
        int v = __shfl_up(s, o);
        if (lane >= o) s += v;
    }
    if (lane == 63) wsum[wid] = s;
    __syncthreads();
    if (tid == 0) {                            // exclusive scan of 16 wave totals
        int run = 0;
#pragma unroll
        for (int w = 0; w < SC_WAVES; ++w) { int t = wsum[w]; wsum[w] = run; run += t; }
    }
    __syncthreads();
    int prefix = (s - sown) + wsum[wid];
    for (int i = lo; i < hi; ++i) {
        int c = hist[i];
        binbase[i] = (unsigned short)prefix;
        prefix += c;
        hist[i] = (c > 0) ? atomicAdd(&cursor[i], c) : 0;   // hist -> gbase
    }
    __syncthreads();

    // Phase 3 — stage records at sorted positions (pure compute, no re-read).
#pragma unroll
    for (int j = 0; j < SC_EPT; ++j) {
        if (rp[j] < 0) continue;
        int bkt  = rp[j] >> 19;
        int drow = (rp[j] >> 14) & (RB - 1);
        int rank = rp[j] & 16383;
        int pos = (int)binbase[bkt] + rank;
        srec[pos] = ((u64)__float_as_uint(vv[j]) << 32) | ((u64)(uint)sv[j] << 6) | (u64)drow;
        bkts[pos] = (unsigned short)bkt;
    }
    __syncthreads();

    // Phase 4 — sorted, mostly-contiguous global writes.
    long long rem = E - base_e;
    int total = rem < SC_EDGES ? (int)rem : SC_EDGES;
    for (int i = tid; i < total; i += SC_BLOCK) {
        int bkt   = bkts[i];
        int lrank = i - (int)binbase[bkt];
        int off   = hist[bkt] + lrank;
        if (off < CAP) packed[(size_t)bkt * CAP + off] = srec[i];
    }
}

// K3: atomic-free reduce, 512 threads = 16 slots x 32 batches.
// Stage+rank -> scatter full records into row-sorted LDS (no perm) ->
// each slot register-accumulates 2 rows' contiguous ranges -> transposed
// coalesced store with bias.
#define RD_BLOCK 512
__global__ __launch_bounds__(RD_BLOCK)
void SL_sort_reduce_kernel(const u64* __restrict__ packed, const int* __restrict__ cursor,
                           const __hip_bfloat16* __restrict__ xt,
                           const float* __restrict__ bias,
                           float* __restrict__ out, int M, int CAP) {
    __shared__ u64 ssort[SREC_MAX];
    __shared__ int bins[RB + 1];
    __shared__ float acc[RB][33];

    const int tid  = threadIdx.x;
    const int bkt  = blockIdx.x;
    const int row0 = bkt << RB_SHIFT;
    int nE = cursor[bkt];
    if (nE > CAP) nE = CAP;
    const u64* pb = packed + (size_t)bkt * CAP;

    if (tid < RB + 1) bins[tid] = 0;
    __syncthreads();

    // Stage to registers (coalesced) + per-row rank via 32-bin LDS histogram.
    u64 pr[SREC_MAX / RD_BLOCK];
    int rk[SREC_MAX / RD_BLOCK];
    int rw[SREC_MAX / RD_BLOCK];
#pragma unroll
    for (int i = 0; i < SREC_MAX / RD_BLOCK; ++i) {
        int k = tid + i * RD_BLOCK;
        rk[i] = -1; rw[i] = 0; pr[i] = 0;
        if (k < nE) {
            u64 r = pb[k];
            pr[i] = r;
            rw[i] = (int)(r & (RB - 1));
            rk[i] = atomicAdd(&bins[rw[i] + 1], 1);
        }
    }
    __syncthreads();

    // Exclusive prefix over 32 bins (serial, trivial): bins[r] = start of row r.
    if (tid == 0) {
#pragma unroll
        for (int r = 1; r <= RB; ++r) bins[r] += bins[r - 1];
    }
    __syncthreads();

    // Scatter full records into row-sorted order.
#pragma unroll
    for (int i = 0; i < SREC_MAX / RD_BLOCK; ++i) {
        if (rk[i] >= 0) ssort[bins[rw[i]] + rk[i]] = pr[i];
    }
    __syncthreads();

    // Register accumulation: slot s owns rows 2s..2s+1; lane b owns batch b.
    const int slot = tid >> 5;   // 0..15
    const int b    = tid & 31;
#pragma unroll
    for (int rr = 0; rr < 2; ++rr) {
        const int r  = slot * 2 + rr;
        const int j0 = bins[r];
        const int j1 = bins[r + 1];
        float a0 = 0.0f, a1 = 0.0f, a2 = 0.0f, a3 = 0.0f;
        int j = j0;
        for (; j + 4 <= j1; j += 4) {
            u64 p0 = ssort[j], p1 = ssort[j + 1], p2 = ssort[j + 2], p3 = ssort[j + 3];
            float x0 = __bfloat162float(xt[(size_t)((p0 >> 6) & 0x3FFFFFFu) * 32 + b]);
            float x1 = __bfloat162float(xt[(size_t)((p1 >> 6) & 0x3FFFFFFu) * 32 + b]);
            float x2 = __bfloat162float(xt[(size_t)((p2 >> 6) & 0x3FFFFFFu) * 32 + b]);
            float x3 = __bfloat162float(xt[(size_t)((p3 >> 6) & 0x3FFFFFFu) * 32 + b]);
            a0 += __uint_as_float((uint32_t)(p0 >> 32)) * x0;
            a1 += __uint_as_float((uint32_t)(p1 >> 32)) * x1;
            a2 += __uint_as_float((uint32_t)(p2 >> 32)) * x2;
            a3 += __uint_as_float((uint32_t)(p3 >> 32)) * x3;
        }
        for (; j < j1; ++j) {
            u64 p = ssort[j];
            float xv = __bfloat162float(xt[(size_t)((p >> 6) & 0x3FFFFFFu) * 32 + b]);
            a0 += __uint_as_float((uint32_t)(p >> 32)) * xv;
        }
        acc[r][b] = (a0 + a1) + (a2 + a3);   // unique (r,b) owner: plain write
    }
    __syncthreads();

    // out[b, row0+r] = acc[r][b] + bias[row0+r]; consecutive tid -> consecutive r.
    for (int i = tid; i < RB * 32; i += RD_BLOCK) {
        int rr = i & (RB - 1);
        int bb = i >> RB_SHIFT;
        int m  = row0 + rr;
        if (m < M)
            __builtin_nontemporal_store(acc[rr][bb] + bias[m], &out[(size_t)bb * M + m]);
    }
}

// K3 fallback (CAP > SREC_MAX): atomic bucket reduce (R5 structure).
#define RD_K 8
__global__ __launch_bounds__(256)
void SL_bucket_reduce_kernel(const u64* __restrict__ packed, const int* __restrict__ cursor,
                             const __hip_bfloat16* __restrict__ xt,
                             const float* __restrict__ bias,
                             float* __restrict__ out, int M, int CAP) {
    __shared__ float acc[RB][33];
    const int tid = threadIdx.x;
    for (int i = tid; i < RB * 33; i += 256) ((float*)acc)[i] = 0.0f;
    __syncthreads();

    const int bkt  = blockIdx.x;
    const int row0 = bkt << RB_SHIFT;
    int nE = cursor[bkt];
    if (nE > CAP) nE = CAP;
    const u64* pb = packed + (size_t)bkt * CAP;

    const int slot = tid >> 5;
    const int b    = tid & 31;

    for (int base = slot * RD_K; base < nE; base += 8 * RD_K) {
        u64 p[RD_K];
#pragma unroll
        for (int j = 0; j < RD_K; ++j) {
            int k = base + j;
            p[j] = (k < nE) ? pb[k] : 0ULL;
        }
        float xv[RD_K];
#pragma unroll
        for (int j = 0; j < RD_K; ++j) {
            int s = (int)((p[j] >> 6) & 0x3FFFFFFu);
            xv[j] = __bfloat162float(xt[(size_t)s * 32 + b]);
        }
#pragma unroll
        for (int j = 0; j < RD_K; ++j) {
            float v = __uint_as_float((uint32_t)(p[j] >> 32));
            atomicAdd(&acc[(int)(p[j] & (RB - 1))][b], v * xv[j]);
        }
    }
    __syncthreads();

    for (int i = tid; i < RB * 32; i += 256) {
        int rr = i & (RB - 1);
        int bb = i >> RB_SHIFT;
        int m  = row0 + rr;
        if (m < M)
            __builtin_nontemporal_store(acc[rr][bb] + bias[m], &out[(size_t)bb * M + m]);
    }
}

// ----------------- tier-2 fallback: direct atomic scatter ------------------

__global__ void SL_detect_zero_kernel(const uint32_t* __restrict__ raw, int* __restrict__ flag,
                                      int* __restrict__ cursor, int NB) {
    int gid = blockIdx.x * blockDim.x + threadIdx.x;
    if (gid == 0) {
        int is64 = 1;
        for (int i = 1; i < 64; i += 2) {
            if (raw[i] != 0u) { is64 = 0; break; }
        }
        *flag = is64;
    }
    for (int i = gid; i < NB; i += gridDim.x * blockDim.x) cursor[i] = 0;
}

__global__ void SL_zero_kernel(int* __restrict__ p, long long n) {
    long long tid = (long long)blockIdx.x * blockDim.x + threadIdx.x;
    if (tid < n) p[tid] = 0;
}

__global__ void SL_convert_kernel(const int* __restrict__ raw, int* __restrict__ out,
                                  long long n, const int* __restrict__ flag) {
    long long tid = (long long)blockIdx.x * blockDim.x + threadIdx.x;
    if (tid >= n) return;
    const int is64 = *flag;
    out[tid] = is64 ? raw[tid * 2] : raw[tid];
}

__global__ void SL_prep_flat_kernel(const float* __restrict__ x, float* __restrict__ xt, int N) {
    long long tid = (long long)blockIdx.x * blockDim.x + threadIdx.x;
    long long totalN = (long long)N * 32;
    if (tid >= totalN) return;
    int n = (int)(tid >> 5);
    int b = (int)(tid & 31);
    xt[tid] = x[(long long)b * N + n];
}

__global__ void SL_scatter_kernel(const int* __restrict__ src, const int* __restrict__ dst,
                                  const float* __restrict__ vals, const float* __restrict__ xt,
                                  float* __restrict__ out_t, long long E) {
    long long tid = (long long)blockIdx.x * blockDim.x + threadIdx.x;
    long long e = tid >> 3;
    if (e >= E) return;
    int b0 = (int)(tid & 7) * 4;
    int s = src[e];
    int d = dst[e];
    float v = vals[e];
    const float4 xv = *reinterpret_cast<const float4*>(xt + (long long)s * 32 + b0);
    float* op = out_t + (long long)d * 32 + b0;
#if defined(__HIP_DEVICE_COMPILE__)
    unsafeAtomicAdd(op + 0, v * xv.x);
    unsafeAtomicAdd(op + 1, v * xv.y);
    unsafeAtomicAdd(op + 2, v * xv.z);
    unsafeAtomicAdd(op + 3, v * xv.w);
#endif
}

__global__ void SL_finalize_kernel(const float* __restrict__ out_t, const float* __restrict__ bias,
                                   float* __restrict__ out, int M) {
    __shared__ float tile[32][33];
    int m0 = blockIdx.x * 32;
    int tx = threadIdx.x;
    int ty = threadIdx.y;
    int m = m0 + ty;
    if (m < M) tile[ty][tx] = out_t[(long long)m * 32 + tx];
    __syncthreads();
    int mm = m0 + tx;
    if (mm < M) out[(long long)ty * M + mm] = tile[tx][ty] + bias[mm];
}

// ----------------- tier-3 fallback: fully generic ------------------

__global__ void SL_init_out_kernel(const float* __restrict__ bias, float* __restrict__ out,
                                   int M, long long total) {
    long long tid = (long long)blockIdx.x * blockDim.x + threadIdx.x;
    if (tid < total) out[tid] = bias[tid % M];
}

__global__ void SL_scatter_direct_kernel(const int* __restrict__ raw, const int* __restrict__ flag,
                                         const float* __restrict__ vals, const float* __restrict__ x,
                                         float* __restrict__ out, long long E, int N, int M, int B) {
    long long e = (long long)blockIdx.x * blockDim.x + threadIdx.x;
    if (e >= E) return;
    const int is64 = *flag;
    long long s = is64 ? raw[2 * e] : raw[e];
    long long d = is64 ? raw[2 * (E + e)] : raw[E + e];
    float v = vals[e];
    for (int b = 0; b < B; ++b) {
#if defined(__HIP_DEVICE_COMPILE__)
        unsafeAtomicAdd(&out[(long long)b * M + d], v * x[(long long)b * N + s]);
#endif
    }
}

extern "C" void kernel_launch(void* const* d_in, const int* in_sizes, int n_in,
                              void* d_out, int out_size, void* d_ws, size_t ws_size,
                              hipStream_t stream) {
    const float* x       = (const float*)d_in[0];
    const int*   idx_raw = (const int*)d_in[1];
    const float* vals    = (const float*)d_in[2];
    const float* bias    = (const float*)d_in[3];
    float*       out     = (float*)d_out;

    const long long twoE = in_sizes[1];
    const long long E    = twoE / 2;
    const int M = in_sizes[3];
    const int B = out_size / M;
    const int N = in_sizes[0] / B;

    const int NB = (M + RB - 1) >> RB_SHIFT;
    double mean = (double)E / (double)NB;
    int CAP = (int)(mean + 8.0 * sqrt(mean > 1.0 ? mean : 1.0) + 128.0);
    CAP = (CAP + 63) & ~63;

    const size_t xt_b  = (((size_t)N * 32 * sizeof(__hip_bfloat16)) + 255) & ~(size_t)255;
    const size_t pk_b  = (size_t)NB * (size_t)CAP * sizeof(u64);
    const size_t need1 = xt_b + pk_b + (size_t)NB * 4 + 64;
    const size_t need2 = ((size_t)(N + M) * 32 + (size_t)twoE + 1) * sizeof(int);

    // Scatter dynamic LDS: srec (SC_EDGES u64) + hist (NB int) + wsum (16 int)
    // + binbase (NB u16) + bkts (SC_EDGES u16).
    const size_t sc_lds = (size_t)SC_EDGES * 8 + (size_t)NB * 4 + 64
                        + (size_t)NB * 2 + (size_t)SC_EDGES * 2 + 16;

    if (B == 32 && N <= (1 << 26) && NB <= 2047 && ws_size >= need1 && sc_lds <= 64 * 1024) {
        char* ws = (char*)d_ws;
        __hip_bfloat16* xt = (__hip_bfloat16*)ws;
        u64* packed = (u64*)(ws + xt_b);
        int* cursor = (int*)(ws + xt_b + pk_b);
        int* flag   = cursor + NB;

        // prep (fused: transpose + detect + cursor zero). Grid must cover
        // both the N/32 transpose tiles and NB/1024 cursor chunks.
        unsigned pgrid = (unsigned)((N + 31) / 32);
        unsigned cgrid = (unsigned)((NB + 1023) / 1024);
        if (cgrid > pgrid) pgrid = cgrid;
        dim3 pblk(32, 32);
        SL_prep_kernel<<<pgrid, pblk, 0, stream>>>(x, xt, N, (const uint32_t*)idx_raw,
                                                   flag, cursor, NB);

        unsigned sgrid = (unsigned)((E + SC_EDGES - 1) / SC_EDGES);
        SL_bucket_scatter_kernel<<<sgrid, SC_BLOCK, (unsigned)sc_lds, stream>>>(
            idx_raw, flag, vals, packed, cursor, E, NB, CAP);

        if (CAP <= SREC_MAX) {
            SL_sort_reduce_kernel<<<NB, RD_BLOCK, 0, stream>>>(
                packed, cursor, xt, bias, out, M, CAP);
        } else {
            SL_bucket_reduce_kernel<<<NB, 256, 0, stream>>>(
                packed, cursor, xt, bias, out, M, CAP);
        }
    } else if (B == 32 && ws_size >= need2) {
        float* xtf   = (float*)d_ws;
        float* out_t = xtf + (size_t)N * 32;
        int*   idx32 = (int*)(out_t + (size_t)M * 32);
        int*   flag  = idx32 + twoE;

        SL_detect_zero_kernel<<<1, 256, 0, stream>>>((const uint32_t*)idx_raw, flag, flag, 0);
        SL_convert_kernel<<<(unsigned)((twoE + 255) / 256), 256, 0, stream>>>(
            idx_raw, idx32, twoE, flag);
        long long prep_total = (long long)N * 32;
        SL_prep_flat_kernel<<<(unsigned)((prep_total + 255) / 256), 256, 0, stream>>>(x, xtf, N);
        SL_zero_kernel<<<(unsigned)(((long long)M * 32 + 255) / 256), 256, 0, stream>>>(
            (int*)out_t, (long long)M * 32);
        long long sc_total = E * 8;
        SL_scatter_kernel<<<(unsigned)((sc_total + 255) / 256), 256, 0, stream>>>(
            idx32, idx32 + E, vals, xtf, out_t, E);
        dim3 blk(32, 32);
        SL_finalize_kernel<<<(M + 31) / 32, blk, 0, stream>>>(out_t, bias, out, M);
    } else if (ws_size >= sizeof(int)) {
        int* flag = (int*)d_ws;
        SL_detect_zero_kernel<<<1, 256, 0, stream>>>((const uint32_t*)idx_raw, flag, flag, 0);
        long long total = (long long)B * M;
        SL_init_out_kernel<<<(unsigned)((total + 255) / 256), 256, 0, stream>>>(bias, out, M, total);
        SL_scatter_direct_kernel<<<(unsigned)((E + 255) / 256), 256, 0, stream>>>(
            idx_raw, flag, vals, x, out, E, N, M, B);
    }
}

// Round 16
// 63.532 us; speedup vs baseline: 1.2213x; 1.2213x over previous
//
#include <hip/hip_runtime.h>
#include <hip/hip_bf16.h>
#include <cstdint>
#include <cmath>

typedef unsigned long long u64;

// ---------------------------------------------------------------------------
// SparseLinear: out[b, dst[e]] += values[e] * x[b, src[e]]; out += bias
// Round 16: REVERT scatter to the R14 configuration (best known, 68.2us):
// 4096-edge window, int binbase, 53.5KB LDS, 1 block/CU. R15's experiment
// (2048-edge window + u16 binbase for 2 blocks/CU) REGRESSED to 77.6us:
// bank conflicts 250K->690K (u16 same-word serialization) and halved
// per-bucket write runs cost more than the 2x wave-count gained — this
// scatter is bound by write-run locality + LDS width, not occupancy.
// Kept from R15: detect/cursor-zero fused into prep (one fewer launch).
// Journal: 51.2M ds_add_f32 atomics had a ~283us floor (R9 ablation) ->
// counting-sort + register accumulation was the 10x lever. nt-stores on
// scattered 8B records caused 5.4x HBM write amplification (R11->R12).
// Packed edge record: [63:32]=val bits, [31:6]=src, [4:0]=dst&31.
// ---------------------------------------------------------------------------

#define RB        32          // rows per bucket
#define RB_SHIFT  5
#define SREC_MAX  2048        // max records per bucket stageable in LDS (reduce)

// K1: transpose x (32, N) -> xt (N, 32) in bf16 (LDS 32x33 tile), fused with
// int64-detect (block 0) and cursor zeroing (distributed across blocks).
__global__ void SL_prep_kernel(const float* __restrict__ x, __hip_bfloat16* __restrict__ xt,
                               int N, const uint32_t* __restrict__ raw,
                               int* __restrict__ flag, int* __restrict__ cursor, int NB) {
    __shared__ float tile[32][33];
    int tx = threadIdx.x, ty = threadIdx.y;
    int tl = ty * 32 + tx;                       // linear 0..1023
    int gid = blockIdx.x * 1024 + tl;
    if (gid < NB) cursor[gid] = 0;
    if (blockIdx.x == 0 && tl == 0) {
        int is64 = 1;
        for (int i = 1; i < 64; i += 2) {
            if (raw[i] != 0u) { is64 = 0; break; }
        }
        *flag = is64;
    }
    int n0 = blockIdx.x * 32;
    int n = n0 + tx;
    if (n < N) tile[tx][ty] = x[(size_t)ty * N + n];
    __syncthreads();
    int n2 = n0 + ty;
    if (n2 < N) xt[(size_t)n2 * 32 + tx] = __float2bfloat16(tile[ty][tx]);
}

// K2: bucket scatter with in-block counting sort (R14 configuration).
// Phase 1: per-edge bucket rank via LDS histogram atomics; src/val cached
//          in registers (loads overlap the scan).
// Phase 2: wave-shfl scan of histogram (2 barriers total) + global range
//          reservation.
// Phase 3: stage records into LDS at sorted position (+u16 bucket tag).
// Phase 4: LDS-sequential -> global writes (coalesced per-bucket runs).
#define SC_BLOCK 1024
#define SC_EPT   4
#define SC_EDGES (SC_BLOCK * SC_EPT)   // 4096
#define SC_WAVES (SC_BLOCK / 64)       // 16
__global__ __launch_bounds__(SC_BLOCK)
void SL_bucket_scatter_kernel(const int* __restrict__ raw, const int* __restrict__ flag,
                              const float* __restrict__ vals, u64* __restrict__ packed,
                              int* __restrict__ cursor, long long E, int NB, int CAP) {
    extern __shared__ int lds[];
    int* hist    = lds;                       // NB ints; becomes gbase after phase 2
    int* binbase = hist + NB;                 // NB ints
    int* wsum    = binbase + NB;              // 16 ints
    unsigned short* bkts = (unsigned short*)(wsum + 16);         // SC_EDGES u16
    u64* srec = (u64*)(bkts + SC_EDGES);      // SC_EDGES u64

    const int tid  = threadIdx.x;
    const int lane = tid & 63;
    const int wid  = tid >> 6;
    for (int i = tid; i < NB; i += SC_BLOCK) hist[i] = 0;
    __syncthreads();

    const int is64 = *flag;
    const long long base_e = (long long)blockIdx.x * SC_EDGES;
    const long long* raw64 = (const long long*)raw;

    // Phase 1 — rank + cache src/val in registers.
    int   rp[SC_EPT];
    int   sv[SC_EPT];
    float vv[SC_EPT];
#pragma unroll
    for (int j = 0; j < SC_EPT; ++j) {
        long long e = base_e + tid + (long long)j * SC_BLOCK;
        int v = -1;
        if (e < E) {
            int d = is64 ? (int)raw64[E + e] : raw[E + e];
            sv[j] = is64 ? (int)raw64[e] : raw[e];
            vv[j] = vals[e];
            int bkt = d >> RB_SHIFT;
            int rank = atomicAdd(&hist[bkt], 1);
            v = (bkt << 19) | ((d & (RB - 1)) << 14) | rank;
        } else { sv[j] = 0; vv[j] = 0.0f; }
        rp[j] = v;
    }
    __syncthreads();

    // Phase 2 — wave-shfl scan (block-exclusive binbase) + global reservation.
    const int C = (NB + SC_BLOCK - 1) / SC_BLOCK;    // bins per thread (<=2)
    int lo = tid * C, hi = lo + C;
    if (lo > NB) lo = NB;
    if (hi > NB) hi = NB;
    int sown = 0;
    for (int i = lo; i < hi; ++i) sown += hist[i];
    int s = sown;
#pragma unroll
    for (int o = 1; o < 64; o <<= 1) {        // wave inclusive scan
        int v = __shfl_up(s, o);
        if (lane >= o) s += v;
    }
    if (lane == 63) wsum[wid] = s;
    __syncthreads();
    if (tid == 0) {                            // exclusive scan of 16 wave totals
        int run = 0;
#pragma unroll
        for (int w = 0; w < SC_WAVES; ++w) { int t = wsum[w]; wsum[w] = run; run += t; }
    }
    __syncthreads();
    int prefix = (s - sown) + wsum[wid];
    for (int i = lo; i < hi; ++i) {
        int c = hist[i];
        binbase[i] = prefix;
        prefix += c;
        hist[i] = (c > 0) ? atomicAdd(&cursor[i], c) : 0;   // hist -> gbase
    }
    __syncthreads();

    // Phase 3 — stage records at sorted positions (pure compute, no re-read).
#pragma unroll
    for (int j = 0; j < SC_EPT; ++j) {
        if (rp[j] < 0) continue;
        int bkt  = rp[j] >> 19;
        int drow = (rp[j] >> 14) & (RB - 1);
        int rank = rp[j] & 16383;
        int pos = binbase[bkt] + rank;
        srec[pos] = ((u64)__float_as_uint(vv[j]) << 32) | ((u64)(uint)sv[j] << 6) | (u64)drow;
        bkts[pos] = (unsigned short)bkt;
    }
    __syncthreads();

    // Phase 4 — sorted, mostly-contiguous global writes.
    long long rem = E - base_e;
    int total = rem < SC_EDGES ? (int)rem : SC_EDGES;
    for (int i = tid; i < total; i += SC_BLOCK) {
        int bkt   = bkts[i];
        int lrank = i - binbase[bkt];
        int off   = hist[bkt] + lrank;
        if (off < CAP) packed[(size_t)bkt * CAP + off] = srec[i];
    }
}

// K3: atomic-free reduce, 512 threads = 16 slots x 32 batches.
// Stage+rank -> scatter full records into row-sorted LDS (no perm) ->
// each slot register-accumulates 2 rows' contiguous ranges -> transposed
// coalesced store with bias.
#define RD_BLOCK 512
__global__ __launch_bounds__(RD_BLOCK)
void SL_sort_reduce_kernel(const u64* __restrict__ packed, const int* __restrict__ cursor,
                           const __hip_bfloat16* __restrict__ xt,
                           const float* __restrict__ bias,
                           float* __restrict__ out, int M, int CAP) {
    __shared__ u64 ssort[SREC_MAX];
    __shared__ int bins[RB + 1];
    __shared__ float acc[RB][33];

    const int tid  = threadIdx.x;
    const int bkt  = blockIdx.x;
    const int row0 = bkt << RB_SHIFT;
    int nE = cursor[bkt];
    if (nE > CAP) nE = CAP;
    const u64* pb = packed + (size_t)bkt * CAP;

    if (tid < RB + 1) bins[tid] = 0;
    __syncthreads();

    // Stage to registers (coalesced) + per-row rank via 32-bin LDS histogram.
    u64 pr[SREC_MAX / RD_BLOCK];
    int rk[SREC_MAX / RD_BLOCK];
    int rw[SREC_MAX / RD_BLOCK];
#pragma unroll
    for (int i = 0; i < SREC_MAX / RD_BLOCK; ++i) {
        int k = tid + i * RD_BLOCK;
        rk[i] = -1; rw[i] = 0; pr[i] = 0;
        if (k < nE) {
            u64 r = pb[k];
            pr[i] = r;
            rw[i] = (int)(r & (RB - 1));
            rk[i] = atomicAdd(&bins[rw[i] + 1], 1);
        }
    }
    __syncthreads();

    // Exclusive prefix over 32 bins (serial, trivial): bins[r] = start of row r.
    if (tid == 0) {
#pragma unroll
        for (int r = 1; r <= RB; ++r) bins[r] += bins[r - 1];
    }
    __syncthreads();

    // Scatter full records into row-sorted order.
#pragma unroll
    for (int i = 0; i < SREC_MAX / RD_BLOCK; ++i) {
        if (rk[i] >= 0) ssort[bins[rw[i]] + rk[i]] = pr[i];
    }
    __syncthreads();

    // Register accumulation: slot s owns rows 2s..2s+1; lane b owns batch b.
    const int slot = tid >> 5;   // 0..15
    const int b    = tid & 31;
#pragma unroll
    for (int rr = 0; rr < 2; ++rr) {
        const int r  = slot * 2 + rr;
        const int j0 = bins[r];
        const int j1 = bins[r + 1];
        float a0 = 0.0f, a1 = 0.0f, a2 = 0.0f, a3 = 0.0f;
        int j = j0;
        for (; j + 4 <= j1; j += 4) {
            u64 p0 = ssort[j], p1 = ssort[j + 1], p2 = ssort[j + 2], p3 = ssort[j + 3];
            float x0 = __bfloat162float(xt[(size_t)((p0 >> 6) & 0x3FFFFFFu) * 32 + b]);
            float x1 = __bfloat162float(xt[(size_t)((p1 >> 6) & 0x3FFFFFFu) * 32 + b]);
            float x2 = __bfloat162float(xt[(size_t)((p2 >> 6) & 0x3FFFFFFu) * 32 + b]);
            float x3 = __bfloat162float(xt[(size_t)((p3 >> 6) & 0x3FFFFFFu) * 32 + b]);
            a0 += __uint_as_float((uint32_t)(p0 >> 32)) * x0;
            a1 += __uint_as_float((uint32_t)(p1 >> 32)) * x1;
            a2 += __uint_as_float((uint32_t)(p2 >> 32)) * x2;
            a3 += __uint_as_float((uint32_t)(p3 >> 32)) * x3;
        }
        for (; j < j1; ++j) {
            u64 p = ssort[j];
            float xv = __bfloat162float(xt[(size_t)((p >> 6) & 0x3FFFFFFu) * 32 + b]);
            a0 += __uint_as_float((uint32_t)(p >> 32)) * xv;
        }
        acc[r][b] = (a0 + a1) + (a2 + a3);   // unique (r,b) owner: plain write
    }
    __syncthreads();

    // out[b, row0+r] = acc[r][b] + bias[row0+r]; consecutive tid -> consecutive r.
    for (int i = tid; i < RB * 32; i += RD_BLOCK) {
        int rr = i & (RB - 1);
        int bb = i >> RB_SHIFT;
        int m  = row0 + rr;
        if (m < M)
            __builtin_nontemporal_store(acc[rr][bb] + bias[m], &out[(size_t)bb * M + m]);
    }
}

// K3 fallback (CAP > SREC_MAX): atomic bucket reduce (R5 structure).
#define RD_K 8
__global__ __launch_bounds__(256)
void SL_bucket_reduce_kernel(const u64* __restrict__ packed, const int* __restrict__ cursor,
                             const __hip_bfloat16* __restrict__ xt,
                             const float* __restrict__ bias,
                             float* __restrict__ out, int M, int CAP) {
    __shared__ float acc[RB][33];
    const int tid = threadIdx.x;
    for (int i = tid; i < RB * 33; i += 256) ((float*)acc)[i] = 0.0f;
    __syncthreads();

    const int bkt  = blockIdx.x;
    const int row0 = bkt << RB_SHIFT;
    int nE = cursor[bkt];
    if (nE > CAP) nE = CAP;
    const u64* pb = packed + (size_t)bkt * CAP;

    const int slot = tid >> 5;
    const int b    = tid & 31;

    for (int base = slot * RD_K; base < nE; base += 8 * RD_K) {
        u64 p[RD_K];
#pragma unroll
        for (int j = 0; j < RD_K; ++j) {
            int k = base + j;
            p[j] = (k < nE) ? pb[k] : 0ULL;
        }
        float xv[RD_K];
#pragma unroll
        for (int j = 0; j < RD_K; ++j) {
            int s = (int)((p[j] >> 6) & 0x3FFFFFFu);
            xv[j] = __bfloat162float(xt[(size_t)s * 32 + b]);
        }
#pragma unroll
        for (int j = 0; j < RD_K; ++j) {
            float v = __uint_as_float((uint32_t)(p[j] >> 32));
            atomicAdd(&acc[(int)(p[j] & (RB - 1))][b], v * xv[j]);
        }
    }
    __syncthreads();

    for (int i = tid; i < RB * 32; i += 256) {
        int rr = i & (RB - 1);
        int bb = i >> RB_SHIFT;
        int m  = row0 + rr;
        if (m < M)
            __builtin_nontemporal_store(acc[rr][bb] + bias[m], &out[(size_t)bb * M + m]);
    }
}

// ----------------- tier-2 fallback: direct atomic scatter ------------------

__global__ void SL_detect_zero_kernel(const uint32_t* __restrict__ raw, int* __restrict__ flag,
                                      int* __restrict__ cursor, int NB) {
    int gid = blockIdx.x * blockDim.x + threadIdx.x;
    if (gid == 0) {
        int is64 = 1;
        for (int i = 1; i < 64; i += 2) {
            if (raw[i] != 0u) { is64 = 0; break; }
        }
        *flag = is64;
    }
    for (int i = gid; i < NB; i += gridDim.x * blockDim.x) cursor[i] = 0;
}

__global__ void SL_zero_kernel(int* __restrict__ p, long long n) {
    long long tid = (long long)blockIdx.x * blockDim.x + threadIdx.x;
    if (tid < n) p[tid] = 0;
}

__global__ void SL_convert_kernel(const int* __restrict__ raw, int* __restrict__ out,
                                  long long n, const int* __restrict__ flag) {
    long long tid = (long long)blockIdx.x * blockDim.x + threadIdx.x;
    if (tid >= n) return;
    const int is64 = *flag;
    out[tid] = is64 ? raw[tid * 2] : raw[tid];
}

__global__ void SL_prep_flat_kernel(const float* __restrict__ x, float* __restrict__ xt, int N) {
    long long tid = (long long)blockIdx.x * blockDim.x + threadIdx.x;
    long long totalN = (long long)N * 32;
    if (tid >= totalN) return;
    int n = (int)(tid >> 5);
    int b = (int)(tid & 31);
    xt[tid] = x[(long long)b * N + n];
}

__global__ void SL_scatter_kernel(const int* __restrict__ src, const int* __restrict__ dst,
                                  const float* __restrict__ vals, const float* __restrict__ xt,
                                  float* __restrict__ out_t, long long E) {
    long long tid = (long long)blockIdx.x * blockDim.x + threadIdx.x;
    long long e = tid >> 3;
    if (e >= E) return;
    int b0 = (int)(tid & 7) * 4;
    int s = src[e];
    int d = dst[e];
    float v = vals[e];
    const float4 xv = *reinterpret_cast<const float4*>(xt + (long long)s * 32 + b0);
    float* op = out_t + (long long)d * 32 + b0;
#if defined(__HIP_DEVICE_COMPILE__)
    unsafeAtomicAdd(op + 0, v * xv.x);
    unsafeAtomicAdd(op + 1, v * xv.y);
    unsafeAtomicAdd(op + 2, v * xv.z);
    unsafeAtomicAdd(op + 3, v * xv.w);
#endif
}

__global__ void SL_finalize_kernel(const float* __restrict__ out_t, const float* __restrict__ bias,
                                   float* __restrict__ out, int M) {
    __shared__ float tile[32][33];
    int m0 = blockIdx.x * 32;
    int tx = threadIdx.x;
    int ty = threadIdx.y;
    int m = m0 + ty;
    if (m < M) tile[ty][tx] = out_t[(long long)m * 32 + tx];
    __syncthreads();
    int mm = m0 + tx;
    if (mm < M) out[(long long)ty * M + mm] = tile[tx][ty] + bias[mm];
}

// ----------------- tier-3 fallback: fully generic ------------------

__global__ void SL_init_out_kernel(const float* __restrict__ bias, float* __restrict__ out,
                                   int M, long long total) {
    long long tid = (long long)blockIdx.x * blockDim.x + threadIdx.x;
    if (tid < total) out[tid] = bias[tid % M];
}

__global__ void SL_scatter_direct_kernel(const int* __restrict__ raw, const int* __restrict__ flag,
                                         const float* __restrict__ vals, const float* __restrict__ x,
                                         float* __restrict__ out, long long E, int N, int M, int B) {
    long long e = (long long)blockIdx.x * blockDim.x + threadIdx.x;
    if (e >= E) return;
    const int is64 = *flag;
    long long s = is64 ? raw[2 * e] : raw[e];
    long long d = is64 ? raw[2 * (E + e)] : raw[E + e];
    float v = vals[e];
    for (int b = 0; b < B; ++b) {
#if defined(__HIP_DEVICE_COMPILE__)
        unsafeAtomicAdd(&out[(long long)b * M + d], v * x[(long long)b * N + s]);
#endif
    }
}

extern "C" void kernel_launch(void* const* d_in, const int* in_sizes, int n_in,
                              void* d_out, int out_size, void* d_ws, size_t ws_size,
                              hipStream_t stream) {
    const float* x       = (const float*)d_in[0];
    const int*   idx_raw = (const int*)d_in[1];
    const float* vals    = (const float*)d_in[2];
    const float* bias    = (const float*)d_in[3];
    float*       out     = (float*)d_out;

    const long long twoE = in_sizes[1];
    const long long E    = twoE / 2;
    const int M = in_sizes[3];
    const int B = out_size / M;
    const int N = in_sizes[0] / B;

    const int NB = (M + RB - 1) >> RB_SHIFT;
    double mean = (double)E / (double)NB;
    int CAP = (int)(mean + 8.0 * sqrt(mean > 1.0 ? mean : 1.0) + 128.0);
    CAP = (CAP + 63) & ~63;

    const size_t xt_b  = (((size_t)N * 32 * sizeof(__hip_bfloat16)) + 255) & ~(size_t)255;
    const size_t pk_b  = (size_t)NB * (size_t)CAP * sizeof(u64);
    const size_t need1 = xt_b + pk_b + (size_t)NB * 4 + 64;
    const size_t need2 = ((size_t)(N + M) * 32 + (size_t)twoE + 1) * sizeof(int);

    // Scatter dynamic LDS: hist + binbase (NB ints each) + wsum (16 ints)
    // + bkts (SC_EDGES u16) + srec (SC_EDGES u64).
    const size_t sc_lds = (size_t)(2 * NB + 16) * 4
                        + (size_t)SC_EDGES * 2 + (size_t)SC_EDGES * 8;

    if (B == 32 && N <= (1 << 26) && NB <= 2047 && ws_size >= need1 && sc_lds <= 64 * 1024) {
        char* ws = (char*)d_ws;
        __hip_bfloat16* xt = (__hip_bfloat16*)ws;
        u64* packed = (u64*)(ws + xt_b);
        int* cursor = (int*)(ws + xt_b + pk_b);
        int* flag   = cursor + NB;

        // prep (fused: transpose + detect + cursor zero). Grid must cover
        // both the N/32 transpose tiles and NB/1024 cursor chunks.
        unsigned pgrid = (unsigned)((N + 31) / 32);
        unsigned cgrid = (unsigned)((NB + 1023) / 1024);
        if (cgrid > pgrid) pgrid = cgrid;
        dim3 pblk(32, 32);
        SL_prep_kernel<<<pgrid, pblk, 0, stream>>>(x, xt, N, (const uint32_t*)idx_raw,
                                                   flag, cursor, NB);

        unsigned sgrid = (unsigned)((E + SC_EDGES - 1) / SC_EDGES);
        SL_bucket_scatter_kernel<<<sgrid, SC_BLOCK, (unsigned)sc_lds, stream>>>(
            idx_raw, flag, vals, packed, cursor, E, NB, CAP);

        if (CAP <= SREC_MAX) {
            SL_sort_reduce_kernel<<<NB, RD_BLOCK, 0, stream>>>(
                packed, cursor, xt, bias, out, M, CAP);
        } else {
            SL_bucket_reduce_kernel<<<NB, 256, 0, stream>>>(
                packed, cursor, xt, bias, out, M, CAP);
        }
    } else if (B == 32 && ws_size >= need2) {
        float* xtf   = (float*)d_ws;
        float* out_t = xtf + (size_t)N * 32;
        int*   idx32 = (int*)(out_t + (size_t)M * 32);
        int*   flag  = idx32 + twoE;

        SL_detect_zero_kernel<<<1, 256, 0, stream>>>((const uint32_t*)idx_raw, flag, flag, 0);
        SL_convert_kernel<<<(unsigned)((twoE + 255) / 256), 256, 0, stream>>>(
            idx_raw, idx32, twoE, flag);
        long long prep_total = (long long)N * 32;
        SL_prep_flat_kernel<<<(unsigned)((prep_total + 255) / 256), 256, 0, stream>>>(x, xtf, N);
        SL_zero_kernel<<<(unsigned)(((long long)M * 32 + 255) / 256), 256, 0, stream>>>(
            (int*)out_t, (long long)M * 32);
        long long sc_total = E * 8;
        SL_scatter_kernel<<<(unsigned)((sc_total + 255) / 256), 256, 0, stream>>>(
            idx32, idx32 + E, vals, xtf, out_t, E);
        dim3 blk(32, 32);
        SL_finalize_kernel<<<(M + 31) / 32, blk, 0, stream>>>(out_t, bias, out, M);
    } else if (ws_size >= sizeof(int)) {
        int* flag = (int*)d_ws;
        SL_detect_zero_kernel<<<1, 256, 0, stream>>>((const uint32_t*)idx_raw, flag, flag, 0);
        long long total = (long long)B * M;
        SL_init_out_kernel<<<(unsigned)((total + 255) / 256), 256, 0, stream>>>(bias, out, M, total);
        SL_scatter_direct_kernel<<<(unsigned)((E + 255) / 256), 256, 0, stream>>>(
            idx_raw, flag, vals, x, out, E, N, M, B);
    }
}

// Round 17
// 50.736 us; speedup vs baseline: 1.5293x; 1.2522x over previous
//
#include <hip/hip_runtime.h>
#include <hip/hip_bf16.h>
#include <cstdint>
#include <cmath>

typedef unsigned long long u64;

// ---------------------------------------------------------------------------
// SparseLinear: out[b, dst[e]] += values[e] * x[b, src[e]]; out += bias
// Round 17: bucket size 32 -> 64 rows (NB 1563 -> 782). R15 proved write-run
// length is the scatter's binding resource (halving runs regressed 14%);
// doubling bucket size doubles per-bucket write runs (~2.6 -> ~5.2 recs)
// and halves scattered-write transactions, with scatter LDS SHRINKING
// (47.3KB). Record format: val32 | src26 | drow6 = exactly 64 bits.
// Reduce: CAP~2560 staged in LDS, acc[64][33], 16 slots x 4 rows, ~29KB.
// Journal: 51.2M ds_add_f32 atomics had a ~283us floor (R9 ablation) ->
// counting-sort + register accumulation was the 10x lever. nt-stores on
// scattered 8B records caused 5.4x HBM write amplification (R11->R12).
// ---------------------------------------------------------------------------

#define RB        64          // rows per bucket
#define RB_SHIFT  6
#define SREC_MAX  2560        // max records per bucket stageable in LDS (5*512)

// K1: transpose x (32, N) -> xt (N, 32) in bf16 (LDS 32x33 tile), fused with
// int64-detect (block 0) and cursor zeroing (distributed across blocks).
__global__ void SL_prep_kernel(const float* __restrict__ x, __hip_bfloat16* __restrict__ xt,
                               int N, const uint32_t* __restrict__ raw,
                               int* __restrict__ flag, int* __restrict__ cursor, int NB) {
    __shared__ float tile[32][33];
    int tx = threadIdx.x, ty = threadIdx.y;
    int tl = ty * 32 + tx;                       // linear 0..1023
    int gid = blockIdx.x * 1024 + tl;
    if (gid < NB) cursor[gid] = 0;
    if (blockIdx.x == 0 && tl == 0) {
        int is64 = 1;
        for (int i = 1; i < 64; i += 2) {
            if (raw[i] != 0u) { is64 = 0; break; }
        }
        *flag = is64;
    }
    int n0 = blockIdx.x * 32;
    int n = n0 + tx;
    if (n < N) tile[tx][ty] = x[(size_t)ty * N + n];
    __syncthreads();
    int n2 = n0 + ty;
    if (n2 < N) xt[(size_t)n2 * 32 + tx] = __float2bfloat16(tile[ty][tx]);
}

// K2: bucket scatter with in-block counting sort (R14/R16 structure, RB=64).
// rp packing: (bkt<<20) | (drow<<14) | rank   (bkt<1024, drow<64, rank<16384)
#define SC_BLOCK 1024
#define SC_EPT   4
#define SC_EDGES (SC_BLOCK * SC_EPT)   // 4096
#define SC_WAVES (SC_BLOCK / 64)       // 16
__global__ __launch_bounds__(SC_BLOCK)
void SL_bucket_scatter_kernel(const int* __restrict__ raw, const int* __restrict__ flag,
                              const float* __restrict__ vals, u64* __restrict__ packed,
                              int* __restrict__ cursor, long long E, int NB, int CAP) {
    extern __shared__ int lds[];
    int* hist    = lds;                       // NB ints; becomes gbase after phase 2
    int* binbase = hist + NB;                 // NB ints
    int* wsum    = binbase + NB;              // 16 ints
    unsigned short* bkts = (unsigned short*)(wsum + 16);         // SC_EDGES u16
    u64* srec = (u64*)(bkts + SC_EDGES);      // SC_EDGES u64

    const int tid  = threadIdx.x;
    const int lane = tid & 63;
    const int wid  = tid >> 6;
    for (int i = tid; i < NB; i += SC_BLOCK) hist[i] = 0;
    __syncthreads();

    const int is64 = *flag;
    const long long base_e = (long long)blockIdx.x * SC_EDGES;
    const long long* raw64 = (const long long*)raw;

    // Phase 1 — rank + cache src/val in registers.
    int   rp[SC_EPT];
    int   sv[SC_EPT];
    float vv[SC_EPT];
#pragma unroll
    for (int j = 0; j < SC_EPT; ++j) {
        long long e = base_e + tid + (long long)j * SC_BLOCK;
        int v = -1;
        if (e < E) {
            int d = is64 ? (int)raw64[E + e] : raw[E + e];
            sv[j] = is64 ? (int)raw64[e] : raw[e];
            vv[j] = vals[e];
            int bkt = d >> RB_SHIFT;
            int rank = atomicAdd(&hist[bkt], 1);
            v = (bkt << 20) | ((d & (RB - 1)) << 14) | rank;
        } else { sv[j] = 0; vv[j] = 0.0f; }
        rp[j] = v;
    }
    __syncthreads();

    // Phase 2 — wave-shfl scan (block-exclusive binbase) + global reservation.
    const int C = (NB + SC_BLOCK - 1) / SC_BLOCK;    // bins per thread (<=1 here)
    int lo = tid * C, hi = lo + C;
    if (lo > NB) lo = NB;
    if (hi > NB) hi = NB;
    int sown = 0;
    for (int i = lo; i < hi; ++i) sown += hist[i];
    int s = sown;
#pragma unroll
    for (int o = 1; o < 64; o <<= 1) {        // wave inclusive scan
        int v = __shfl_up(s, o);
        if (lane >= o) s += v;
    }
    if (lane == 63) wsum[wid] = s;
    __syncthreads();
    if (tid == 0) {                            // exclusive scan of 16 wave totals
        int run = 0;
#pragma unroll
        for (int w = 0; w < SC_WAVES; ++w) { int t = wsum[w]; wsum[w] = run; run += t; }
    }
    __syncthreads();
    int prefix = (s - sown) + wsum[wid];
    for (int i = lo; i < hi; ++i) {
        int c = hist[i];
        binbase[i] = prefix;
        prefix += c;
        hist[i] = (c > 0) ? atomicAdd(&cursor[i], c) : 0;   // hist -> gbase
    }
    __syncthreads();

    // Phase 3 — stage records at sorted positions (pure compute, no re-read).
#pragma unroll
    for (int j = 0; j < SC_EPT; ++j) {
        if (rp[j] < 0) continue;
        int bkt  = rp[j] >> 20;
        int drow = (rp[j] >> 14) & (RB - 1);
        int rank = rp[j] & 16383;
        int pos = binbase[bkt] + rank;
        srec[pos] = ((u64)__float_as_uint(vv[j]) << 32) | ((u64)(uint)sv[j] << 6) | (u64)drow;
        bkts[pos] = (unsigned short)bkt;
    }
    __syncthreads();

    // Phase 4 — sorted, mostly-contiguous global writes.
    long long rem = E - base_e;
    int total = rem < SC_EDGES ? (int)rem : SC_EDGES;
    for (int i = tid; i < total; i += SC_BLOCK) {
        int bkt   = bkts[i];
        int lrank = i - binbase[bkt];
        int off   = hist[bkt] + lrank;
        if (off < CAP) packed[(size_t)bkt * CAP + off] = srec[i];
    }
}

// K3: atomic-free reduce, 512 threads = 16 slots x 32 batches, 64-row bucket.
// Stage+rank -> scatter full records into row-sorted LDS -> each slot
// register-accumulates 4 rows' contiguous ranges -> transposed store + bias.
#define RD_BLOCK 512
__global__ __launch_bounds__(RD_BLOCK)
void SL_sort_reduce_kernel(const u64* __restrict__ packed, const int* __restrict__ cursor,
                           const __hip_bfloat16* __restrict__ xt,
                           const float* __restrict__ bias,
                           float* __restrict__ out, int M, int CAP) {
    __shared__ u64 ssort[SREC_MAX];
    __shared__ int bins[RB + 1];
    __shared__ float acc[RB][33];

    const int tid  = threadIdx.x;
    const int bkt  = blockIdx.x;
    const int row0 = bkt << RB_SHIFT;
    int nE = cursor[bkt];
    if (nE > CAP) nE = CAP;
    const u64* pb = packed + (size_t)bkt * CAP;

    if (tid < RB + 1) bins[tid] = 0;
    __syncthreads();

    // Stage to registers (coalesced) + per-row rank via 64-bin LDS histogram.
    u64 pr[SREC_MAX / RD_BLOCK];
    int rk[SREC_MAX / RD_BLOCK];
    int rw[SREC_MAX / RD_BLOCK];
#pragma unroll
    for (int i = 0; i < SREC_MAX / RD_BLOCK; ++i) {
        int k = tid + i * RD_BLOCK;
        rk[i] = -1; rw[i] = 0; pr[i] = 0;
        if (k < nE) {
            u64 r = pb[k];
            pr[i] = r;
            rw[i] = (int)(r & (RB - 1));
            rk[i] = atomicAdd(&bins[rw[i] + 1], 1);
        }
    }
    __syncthreads();

    // Exclusive prefix over 64 bins (serial, trivial): bins[r] = start of row r.
    if (tid == 0) {
#pragma unroll
        for (int r = 1; r <= RB; ++r) bins[r] += bins[r - 1];
    }
    __syncthreads();

    // Scatter full records into row-sorted order.
#pragma unroll
    for (int i = 0; i < SREC_MAX / RD_BLOCK; ++i) {
        if (rk[i] >= 0) ssort[bins[rw[i]] + rk[i]] = pr[i];
    }
    __syncthreads();

    // Register accumulation: slot s owns rows 4s..4s+3; lane b owns batch b.
    const int slot = tid >> 5;   // 0..15
    const int b    = tid & 31;
#pragma unroll
    for (int rr = 0; rr < 4; ++rr) {
        const int r  = slot * 4 + rr;
        const int j0 = bins[r];
        const int j1 = bins[r + 1];
        float a0 = 0.0f, a1 = 0.0f, a2 = 0.0f, a3 = 0.0f;
        int j = j0;
        for (; j + 4 <= j1; j += 4) {
            u64 p0 = ssort[j], p1 = ssort[j + 1], p2 = ssort[j + 2], p3 = ssort[j + 3];
            float x0 = __bfloat162float(xt[(size_t)((p0 >> 6) & 0x3FFFFFFu) * 32 + b]);
            float x1 = __bfloat162float(xt[(size_t)((p1 >> 6) & 0x3FFFFFFu) * 32 + b]);
            float x2 = __bfloat162float(xt[(size_t)((p2 >> 6) & 0x3FFFFFFu) * 32 + b]);
            float x3 = __bfloat162float(xt[(size_t)((p3 >> 6) & 0x3FFFFFFu) * 32 + b]);
            a0 += __uint_as_float((uint32_t)(p0 >> 32)) * x0;
            a1 += __uint_as_float((uint32_t)(p1 >> 32)) * x1;
            a2 += __uint_as_float((uint32_t)(p2 >> 32)) * x2;
            a3 += __uint_as_float((uint32_t)(p3 >> 32)) * x3;
        }
        for (; j < j1; ++j) {
            u64 p = ssort[j];
            float xv = __bfloat162float(xt[(size_t)((p >> 6) & 0x3FFFFFFu) * 32 + b]);
            a0 += __uint_as_float((uint32_t)(p >> 32)) * xv;
        }
        acc[r][b] = (a0 + a1) + (a2 + a3);   // unique (r,b) owner: plain write
    }
    __syncthreads();

    // out[b, row0+r] = acc[r][b] + bias[row0+r]; consecutive tid -> consecutive r.
    for (int i = tid; i < RB * 32; i += RD_BLOCK) {
        int rr = i & (RB - 1);
        int bb = i >> RB_SHIFT;
        int m  = row0 + rr;
        if (m < M)
            __builtin_nontemporal_store(acc[rr][bb] + bias[m], &out[(size_t)bb * M + m]);
    }
}

// K3 fallback (CAP > SREC_MAX): atomic bucket reduce.
#define RD_K 8
__global__ __launch_bounds__(256)
void SL_bucket_reduce_kernel(const u64* __restrict__ packed, const int* __restrict__ cursor,
                             const __hip_bfloat16* __restrict__ xt,
                             const float* __restrict__ bias,
                             float* __restrict__ out, int M, int CAP) {
    __shared__ float acc[RB][33];
    const int tid = threadIdx.x;
    for (int i = tid; i < RB * 33; i += 256) ((float*)acc)[i] = 0.0f;
    __syncthreads();

    const int bkt  = blockIdx.x;
    const int row0 = bkt << RB_SHIFT;
    int nE = cursor[bkt];
    if (nE > CAP) nE = CAP;
    const u64* pb = packed + (size_t)bkt * CAP;

    const int slot = tid >> 5;
    const int b    = tid & 31;

    for (int base = slot * RD_K; base < nE; base += 8 * RD_K) {
        u64 p[RD_K];
#pragma unroll
        for (int j = 0; j < RD_K; ++j) {
            int k = base + j;
            p[j] = (k < nE) ? pb[k] : 0ULL;
        }
        float xv[RD_K];
#pragma unroll
        for (int j = 0; j < RD_K; ++j) {
            int s = (int)((p[j] >> 6) & 0x3FFFFFFu);
            xv[j] = __bfloat162float(xt[(size_t)s * 32 + b]);
        }
#pragma unroll
        for (int j = 0; j < RD_K; ++j) {
            float v = __uint_as_float((uint32_t)(p[j] >> 32));
            atomicAdd(&acc[(int)(p[j] & (RB - 1))][b], v * xv[j]);
        }
    }
    __syncthreads();

    for (int i = tid; i < RB * 32; i += 256) {
        int rr = i & (RB - 1);
        int bb = i >> RB_SHIFT;
        int m  = row0 + rr;
        if (m < M)
            __builtin_nontemporal_store(acc[rr][bb] + bias[m], &out[(size_t)bb * M + m]);
    }
}

// ----------------- tier-2 fallback: direct atomic scatter ------------------

__global__ void SL_detect_zero_kernel(const uint32_t* __restrict__ raw, int* __restrict__ flag,
                                      int* __restrict__ cursor, int NB) {
    int gid = blockIdx.x * blockDim.x + threadIdx.x;
    if (gid == 0) {
        int is64 = 1;
        for (int i = 1; i < 64; i += 2) {
            if (raw[i] != 0u) { is64 = 0; break; }
        }
        *flag = is64;
    }
    for (int i = gid; i < NB; i += gridDim.x * blockDim.x) cursor[i] = 0;
}

__global__ void SL_zero_kernel(int* __restrict__ p, long long n) {
    long long tid = (long long)blockIdx.x * blockDim.x + threadIdx.x;
    if (tid < n) p[tid] = 0;
}

__global__ void SL_convert_kernel(const int* __restrict__ raw, int* __restrict__ out,
                                  long long n, const int* __restrict__ flag) {
    long long tid = (long long)blockIdx.x * blockDim.x + threadIdx.x;
    if (tid >= n) return;
    const int is64 = *flag;
    out[tid] = is64 ? raw[tid * 2] : raw[tid];
}

__global__ void SL_prep_flat_kernel(const float* __restrict__ x, float* __restrict__ xt, int N) {
    long long tid = (long long)blockIdx.x * blockDim.x + threadIdx.x;
    long long totalN = (long long)N * 32;
    if (tid >= totalN) return;
    int n = (int)(tid >> 5);
    int b = (int)(tid & 31);
    xt[tid] = x[(long long)b * N + n];
}

__global__ void SL_scatter_kernel(const int* __restrict__ src, const int* __restrict__ dst,
                                  const float* __restrict__ vals, const float* __restrict__ xt,
                                  float* __restrict__ out_t, long long E) {
    long long tid = (long long)blockIdx.x * blockDim.x + threadIdx.x;
    long long e = tid >> 3;
    if (e >= E) return;
    int b0 = (int)(tid & 7) * 4;
    int s = src[e];
    int d = dst[e];
    float v = vals[e];
    const float4 xv = *reinterpret_cast<const float4*>(xt + (long long)s * 32 + b0);
    float* op = out_t + (long long)d * 32 + b0;
#if defined(__HIP_DEVICE_COMPILE__)
    unsafeAtomicAdd(op + 0, v * xv.x);
    unsafeAtomicAdd(op + 1, v * xv.y);
    unsafeAtomicAdd(op + 2, v * xv.z);
    unsafeAtomicAdd(op + 3, v * xv.w);
#endif
}

__global__ void SL_finalize_kernel(const float* __restrict__ out_t, const float* __restrict__ bias,
                                   float* __restrict__ out, int M) {
    __shared__ float tile[32][33];
    int m0 = blockIdx.x * 32;
    int tx = threadIdx.x;
    int ty = threadIdx.y;
    int m = m0 + ty;
    if (m < M) tile[ty][tx] = out_t[(long long)m * 32 + tx];
    __syncthreads();
    int mm = m0 + tx;
    if (mm < M) out[(long long)ty * M + mm] = tile[tx][ty] + bias[mm];
}

// ----------------- tier-3 fallback: fully generic ------------------

__global__ void SL_init_out_kernel(const float* __restrict__ bias, float* __restrict__ out,
                                   int M, long long total) {
    long long tid = (long long)blockIdx.x * blockDim.x + threadIdx.x;
    if (tid < total) out[tid] = bias[tid % M];
}

__global__ void SL_scatter_direct_kernel(const int* __restrict__ raw, const int* __restrict__ flag,
                                         const float* __restrict__ vals, const float* __restrict__ x,
                                         float* __restrict__ out, long long E, int N, int M, int B) {
    long long e = (long long)blockIdx.x * blockDim.x + threadIdx.x;
    if (e >= E) return;
    const int is64 = *flag;
    long long s = is64 ? raw[2 * e] : raw[e];
    long long d = is64 ? raw[2 * (E + e)] : raw[E + e];
    float v = vals[e];
    for (int b = 0; b < B; ++b) {
#if defined(__HIP_DEVICE_COMPILE__)
        unsafeAtomicAdd(&out[(long long)b * M + d], v * x[(long long)b * N + s]);
#endif
    }
}

extern "C" void kernel_launch(void* const* d_in, const int* in_sizes, int n_in,
                              void* d_out, int out_size, void* d_ws, size_t ws_size,
                              hipStream_t stream) {
    const float* x       = (const float*)d_in[0];
    const int*   idx_raw = (const int*)d_in[1];
    const float* vals    = (const float*)d_in[2];
    const float* bias    = (const float*)d_in[3];
    float*       out     = (float*)d_out;

    const long long twoE = in_sizes[1];
    const long long E    = twoE / 2;
    const int M = in_sizes[3];
    const int B = out_size / M;
    const int N = in_sizes[0] / B;

    const int NB = (M + RB - 1) >> RB_SHIFT;
    double mean = (double)E / (double)NB;
    int CAP = (int)(mean + 8.0 * sqrt(mean > 1.0 ? mean : 1.0) + 128.0);
    CAP = (CAP + 63) & ~63;

    const size_t xt_b  = (((size_t)N * 32 * sizeof(__hip_bfloat16)) + 255) & ~(size_t)255;
    const size_t pk_b  = (size_t)NB * (size_t)CAP * sizeof(u64);
    const size_t need1 = xt_b + pk_b + (size_t)NB * 4 + 64;
    const size_t need2 = ((size_t)(N + M) * 32 + (size_t)twoE + 1) * sizeof(int);

    // Scatter dynamic LDS: hist + binbase (NB ints each) + wsum (16 ints)
    // + bkts (SC_EDGES u16) + srec (SC_EDGES u64).
    const size_t sc_lds = (size_t)(2 * NB + 16) * 4
                        + (size_t)SC_EDGES * 2 + (size_t)SC_EDGES * 8;

    if (B == 32 && N <= (1 << 26) && NB <= 1023 && ws_size >= need1 && sc_lds <= 64 * 1024) {
        char* ws = (char*)d_ws;
        __hip_bfloat16* xt = (__hip_bfloat16*)ws;
        u64* packed = (u64*)(ws + xt_b);
        int* cursor = (int*)(ws + xt_b + pk_b);
        int* flag   = cursor + NB;

        // prep (fused: transpose + detect + cursor zero). Grid must cover
        // both the N/32 transpose tiles and NB/1024 cursor chunks.
        unsigned pgrid = (unsigned)((N + 31) / 32);
        unsigned cgrid = (unsigned)((NB + 1023) / 1024);
        if (cgrid > pgrid) pgrid = cgrid;
        dim3 pblk(32, 32);
        SL_prep_kernel<<<pgrid, pblk, 0, stream>>>(x, xt, N, (const uint32_t*)idx_raw,
                                                   flag, cursor, NB);

        unsigned sgrid = (unsigned)((E + SC_EDGES - 1) / SC_EDGES);
        SL_bucket_scatter_kernel<<<sgrid, SC_BLOCK, (unsigned)sc_lds, stream>>>(
            idx_raw, flag, vals, packed, cursor, E, NB, CAP);

        if (CAP <= SREC_MAX) {
            SL_sort_reduce_kernel<<<NB, RD_BLOCK, 0, stream>>>(
                packed, cursor, xt, bias, out, M, CAP);
        } else {
            SL_bucket_reduce_kernel<<<NB, 256, 0, stream>>>(
                packed, cursor, xt, bias, out, M, CAP);
        }
    } else if (B == 32 && ws_size >= need2) {
        float* xtf   = (float*)d_ws;
        float* out_t = xtf + (size_t)N * 32;
        int*   idx32 = (int*)(out_t + (size_t)M * 32);
        int*   flag  = idx32 + twoE;

        SL_detect_zero_kernel<<<1, 256, 0, stream>>>((const uint32_t*)idx_raw, flag, flag, 0);
        SL_convert_kernel<<<(unsigned)((twoE + 255) / 256), 256, 0, stream>>>(
            idx_raw, idx32, twoE, flag);
        long long prep_total = (long long)N * 32;
        SL_prep_flat_kernel<<<(unsigned)((prep_total + 255) / 256), 256, 0, stream>>>(x, xtf, N);
        SL_zero_kernel<<<(unsigned)(((long long)M * 32 + 255) / 256), 256, 0, stream>>>(
            (int*)out_t, (long long)M * 32);
        long long sc_total = E * 8;
        SL_scatter_kernel<<<(unsigned)((sc_total + 255) / 256), 256, 0, stream>>>(
            idx32, idx32 + E, vals, xtf, out_t, E);
        dim3 blk(32, 32);
        SL_finalize_kernel<<<(M + 31) / 32, blk, 0, stream>>>(out_t, bias, out, M);
    } else if (ws_size >= sizeof(int)) {
        int* flag = (int*)d_ws;
        SL_detect_zero_kernel<<<1, 256, 0, stream>>>((const uint32_t*)idx_raw, flag, flag, 0);
        long long total = (long long)B * M;
        SL_init_out_kernel<<<(unsigned)((total + 255) / 256), 256, 0, stream>>>(bias, out, M, total);
        SL_scatter_direct_kernel<<<(unsigned)((E + 255) / 256), 256, 0, stream>>>(
            idx_raw, flag, vals, x, out, E, N, M, B);
    }
}